// Round 2
// baseline (557.089 us; speedup 1.0000x reference)
//
#include <hip/hip_runtime.h>
#include <stdint.h>

// CDSSM: conv1(128ch,k3) -> tanh -> conv2(128ch,k3) -> tanh -> max_t -> proj -> tanh
//        then dots(q·pos, q·negs) -> gamma -> softmax.  B=64,T=2048,D=K=K2=128,L=64,J=2.
// R2: 2 barriers/iter (halo-free windows, stride 124), async-stage split for X
//     (issue loads pre-L1, convert+write during L2), native bf16 casts (cvt_pk).

typedef __bf16 bf16x8 __attribute__((ext_vector_type(8)));
typedef __bf16 bf16x4 __attribute__((ext_vector_type(4)));
typedef float f32x16 __attribute__((ext_vector_type(16)));
typedef unsigned short u16x8 __attribute__((ext_vector_type(8)));

__device__ __forceinline__ unsigned short f2bf(float f) {
  unsigned u = __builtin_bit_cast(unsigned, f);
  u = u + 0x7FFFu + ((u >> 16) & 1u);   // RTNE
  return (unsigned short)(u >> 16);
}

__device__ __forceinline__ float fast_tanh(float x) {
  x = fminf(10.0f, fmaxf(-10.0f, x));
  float t = __builtin_amdgcn_exp2f(x * -2.8853900817779268f);   // e^{-2x}
  return (1.0f - t) * __builtin_amdgcn_rcpf(1.0f + t);
}

// ---------------- prep: fp32 [k][d][f] -> bf16 [br][f][k][d] ----------------
__global__ void prep_kernel(const float* __restrict__ qw1, const float* __restrict__ qw2,
                            const float* __restrict__ dw1, const float* __restrict__ dw2,
                            unsigned short* __restrict__ W1p, unsigned short* __restrict__ W2p) {
  int gid = blockIdx.x * 256 + threadIdx.x;          // 768*256 = 196608 exact
  int which = gid >= 98304;
  int e = gid - which * 98304;
  int br = e / 49152;
  int r  = e % 49152;
  int f  = r / 16384;
  int r2 = r % 16384;
  int k  = r2 / 128;
  int d  = r2 % 128;
  const float* src = which ? (br ? dw2 : qw2) : (br ? dw1 : qw1);
  float v = src[k * 384 + d * 3 + f];
  (which ? W2p : W1p)[e] = f2bf(v);
}

// ---------------- main fused conv kernel ----------------
// LDS layout (dynamic, 131584 B):
//  W1S_OFF : bf16 [2 taps][128 k][128 d], row-swizzled   (65536 B)
//  XS_OFF  : bf16 [128 slot][128 d], swizzled            (32768 B)
//  H1S_OFF : bf16 [126 slot][128 k], swizzled            (32256 B)
//  B1_OFF/B2_OFF : float[128] biases                     (1024 B)
#define W1S_OFF 0
#define XS_OFF  65536
#define H1S_OFF 98304
#define B1_OFF  130560
#define B2_OFF  131072
#define LDS_TOTAL 131584

__global__ __launch_bounds__(512, 2) void cdssm_main(
    const float* __restrict__ q, const float* __restrict__ pos, const float* __restrict__ negs,
    const unsigned short* __restrict__ W1p, const unsigned short* __restrict__ W2p,
    const float* __restrict__ qb1, const float* __restrict__ qb2,
    const float* __restrict__ db1, const float* __restrict__ db2,
    float* __restrict__ hpart) {
  extern __shared__ char lds[];
  const int tid = threadIdx.x;
  const int bid = blockIdx.x;
  const int seq = bid >> 1;
  const int half = bid & 1;
  const int branch = (seq < 64) ? 0 : 1;
  const float* xptr = (seq < 64) ? (q + (size_t)seq * 2048 * 128)
                    : (seq < 128) ? (pos + (size_t)(seq - 64) * 2048 * 128)
                                  : (negs + (size_t)(seq - 128) * 2048 * 128);
  const float* b1g = branch ? db1 : qb1;
  const float* b2g = branch ? db2 : qb2;
  const int lo = half * 1022;
  const int hi = lo + 1022;   // 2*1022 = 2044 = T-4 outputs total

  // ---- stage W1 taps 0,1 into LDS (swizzled) + biases ----
  {
    const unsigned short* w1src = W1p + (size_t)branch * 49152;
    for (int ch = tid; ch < 4096; ch += 512) {       // 65536B / 16B
      int e = ch * 8;
      int f = e >> 14;
      int krow = (e >> 7) & 127;
      int d0 = e & 127;
      u16x8 v = *(const u16x8*)(w1src + ((f * 128 + krow) * 128 + d0));
      *(u16x8*)(lds + W1S_OFF + (f * 128 + krow) * 256 + ((d0 * 2) ^ ((krow & 15) << 4))) = v;
    }
    if (tid < 128) ((float*)(lds + B1_OFF))[tid] = b1g[tid];
    else if (tid < 256) ((float*)(lds + B2_OFF))[tid - 128] = b2g[tid - 128];
  }

  const int lane = tid & 63;
  const int w = tid >> 6;            // 8 waves
  const int lrow = lane & 31;
  const int hi5 = lane >> 5;         // k-group
  const int r0 = (w & 3) * 32;       // output-row tile
  const int cbase = (w >> 2) * 64;   // 2 col tiles of 32
  const int row1 = r0 + lrow;

  // register fragments: W1 tap2 (this wave's rows), all of W2 (this wave's rows)
  bf16x8 a1t2[8], a2s[24];
  {
    const unsigned short* w1src = W1p + (size_t)branch * 49152;
    const unsigned short* w2src = W2p + (size_t)branch * 49152;
#pragma unroll
    for (int kk = 0; kk < 8; ++kk)
      a1t2[kk] = __builtin_bit_cast(bf16x8,
          *(const u16x8*)(w1src + ((2 * 128 + row1) * 128 + kk * 16 + hi5 * 8)));
#pragma unroll
    for (int f = 0; f < 3; ++f)
#pragma unroll
      for (int kk = 0; kk < 8; ++kk)
        a2s[f * 8 + kk] = __builtin_bit_cast(bf16x8,
            *(const u16x8*)(w2src + ((f * 128 + row1) * 128 + kk * 16 + hi5 * 8)));
  }

  const int arow = row1 * 256;                 // + W1S_OFF + f*32768
  const int aswz = (lrow & 15) << 4;
  const int hi16 = hi5 * 16;                   // byte offset of k-group

  float vmax[16];
#pragma unroll
  for (int r = 0; r < 16; ++r) vmax[r] = -2.0f;

  // ---- prologue: stage X window 0 ----
  {
#pragma unroll
    for (int u = 0; u < 4; ++u) {
      int c2 = tid + 512 * u;            // chunk 0..2047
      int slot = c2 >> 4;
      int d0 = (c2 & 15) * 8;
      int t = lo + slot; if (t > 2047) t = 2047;
      const float* src = xptr + ((size_t)t * 128 + d0);
      float4 v0 = *(const float4*)src;
      float4 v1 = *(const float4*)(src + 4);
      bf16x8 o;
      o[0] = (__bf16)v0.x; o[1] = (__bf16)v0.y; o[2] = (__bf16)v0.z; o[3] = (__bf16)v0.w;
      o[4] = (__bf16)v1.x; o[5] = (__bf16)v1.y; o[6] = (__bf16)v1.z; o[7] = (__bf16)v1.w;
      *(bf16x8*)(lds + XS_OFF + slot * 256 + ((d0 * 2) ^ ((slot & 15) << 4))) = o;
    }
  }
  __syncthreads();   // X(0) + W1 + biases ready

  for (int it = 0; it < 9; ++it) {
    const int base = lo + it * 124;

    // ---- issue global loads for next window (latency hides under L1) ----
    float4 sreg[8];
    if (it < 8) {
      const int basen = base + 124;
#pragma unroll
      for (int u = 0; u < 4; ++u) {
        int c2 = tid + 512 * u;
        int slot = c2 >> 4;
        int d0 = (c2 & 15) * 8;
        int t = basen + slot; if (t > 2047) t = 2047;
        const float* src = xptr + ((size_t)t * 128 + d0);
        sreg[2 * u]     = *(const float4*)src;
        sreg[2 * u + 1] = *(const float4*)(src + 4);
      }
    }

    // ---- layer 1: h1[k, s] = tanh(b1 + sum_f sum_d W1[k,d,f] * X[base+s+f, d]) ----
    {
      int xb[2][3], xz[2][3];
#pragma unroll
      for (int cf = 0; cf < 2; ++cf)
#pragma unroll
        for (int f = 0; f < 3; ++f) {
          int s = cbase + cf * 32 + lrow + f; if (s > 127) s = 127;
          xb[cf][f] = XS_OFF + s * 256;
          xz[cf][f] = (s & 15) << 4;
        }
      f32x16 acc0, acc1;
#pragma unroll
      for (int r = 0; r < 16; ++r) { acc0[r] = 0.f; acc1[r] = 0.f; }
#pragma unroll
      for (int f = 0; f < 2; ++f)
#pragma unroll
        for (int kk = 0; kk < 8; ++kk) {
          bf16x8 af = __builtin_bit_cast(bf16x8,
              *(const u16x8*)(lds + W1S_OFF + f * 32768 + arow + ((kk * 32 + hi16) ^ aswz)));
          bf16x8 b0 = __builtin_bit_cast(bf16x8,
              *(const u16x8*)(lds + xb[0][f] + ((kk * 32 + hi16) ^ xz[0][f])));
          acc0 = __builtin_amdgcn_mfma_f32_32x32x16_bf16(af, b0, acc0, 0, 0, 0);
          bf16x8 b1v = __builtin_bit_cast(bf16x8,
              *(const u16x8*)(lds + xb[1][f] + ((kk * 32 + hi16) ^ xz[1][f])));
          acc1 = __builtin_amdgcn_mfma_f32_32x32x16_bf16(af, b1v, acc1, 0, 0, 0);
        }
#pragma unroll
      for (int kk = 0; kk < 8; ++kk) {
        bf16x8 b0 = __builtin_bit_cast(bf16x8,
            *(const u16x8*)(lds + xb[0][2] + ((kk * 32 + hi16) ^ xz[0][2])));
        acc0 = __builtin_amdgcn_mfma_f32_32x32x16_bf16(a1t2[kk], b0, acc0, 0, 0, 0);
        bf16x8 b1v = __builtin_bit_cast(bf16x8,
            *(const u16x8*)(lds + xb[1][2] + ((kk * 32 + hi16) ^ xz[1][2])));
        acc1 = __builtin_amdgcn_mfma_f32_32x32x16_bf16(a1t2[kk], b1v, acc1, 0, 0, 0);
      }
#pragma unroll
      for (int cf = 0; cf < 2; ++cf) {
        const f32x16 acc = cf ? acc1 : acc0;
        int s = cbase + cf * 32 + lrow;       // C layout: col = lane&31
        if (s < 126) {
          int wb = H1S_OFF + s * 256;
          int wz = (s & 15) << 4;
#pragma unroll
          for (int qd = 0; qd < 4; ++qd) {
            int k0 = r0 + qd * 8 + hi5 * 4;   // C rows: (reg&3)+8*(reg>>2)+4*hi
            float4 bq = *(const float4*)(lds + B1_OFF + k0 * 4);
            bf16x4 hv;
            hv[0] = (__bf16)fast_tanh(acc[qd * 4 + 0] + bq.x);
            hv[1] = (__bf16)fast_tanh(acc[qd * 4 + 1] + bq.y);
            hv[2] = (__bf16)fast_tanh(acc[qd * 4 + 2] + bq.z);
            hv[3] = (__bf16)fast_tanh(acc[qd * 4 + 3] + bq.w);
            *(bf16x4*)(lds + wb + ((k0 * 2) ^ wz)) = hv;
          }
        }
      }
    }
    __syncthreads();   // (1) h1 ready; all waves done reading X(it)

    // ---- layer 2: y2[k2, s2] = tanh(b2 + sum_f sum_c W2[k2,c,f] * h1[c, s2+f]) ----
    {
      int hb[2][3], hz[2][3];
#pragma unroll
      for (int cf = 0; cf < 2; ++cf)
#pragma unroll
        for (int f = 0; f < 3; ++f) {
          int s = cbase + cf * 32 + lrow + f; if (s > 125) s = 125;
          hb[cf][f] = H1S_OFF + s * 256;
          hz[cf][f] = (s & 15) << 4;
        }
      f32x16 acc0, acc1;
#pragma unroll
      for (int r = 0; r < 16; ++r) { acc0[r] = 0.f; acc1[r] = 0.f; }
#pragma unroll
      for (int f = 0; f < 3; ++f)
#pragma unroll
        for (int kk = 0; kk < 8; ++kk) {
          bf16x8 b0 = __builtin_bit_cast(bf16x8,
              *(const u16x8*)(lds + hb[0][f] + ((kk * 32 + hi16) ^ hz[0][f])));
          acc0 = __builtin_amdgcn_mfma_f32_32x32x16_bf16(a2s[f * 8 + kk], b0, acc0, 0, 0, 0);
          bf16x8 b1v = __builtin_bit_cast(bf16x8,
              *(const u16x8*)(lds + hb[1][f] + ((kk * 32 + hi16) ^ hz[1][f])));
          acc1 = __builtin_amdgcn_mfma_f32_32x32x16_bf16(a2s[f * 8 + kk], b1v, acc1, 0, 0, 0);
        }

      // ---- convert + write next X window (loads issued pre-L1; waits here) ----
      if (it < 8) {
#pragma unroll
        for (int u = 0; u < 4; ++u) {
          int c2 = tid + 512 * u;
          int slot = c2 >> 4;
          int d0 = (c2 & 15) * 8;
          const float* f0 = (const float*)&sreg[2 * u];
          bf16x8 o;
#pragma unroll
          for (int j = 0; j < 8; ++j) o[j] = (__bf16)f0[j];
          *(bf16x8*)(lds + XS_OFF + slot * 256 + ((d0 * 2) ^ ((slot & 15) << 4))) = o;
        }
      }

#pragma unroll
      for (int cf = 0; cf < 2; ++cf) {
        const f32x16 acc = cf ? acc1 : acc0;
        int s2 = cbase + cf * 32 + lrow;
        bool valid = (s2 < 124) && (base + s2 < hi);
#pragma unroll
        for (int qd = 0; qd < 4; ++qd) {
          int k0 = r0 + qd * 8 + hi5 * 4;
          float4 bq = *(const float4*)(lds + B2_OFF + k0 * 4);
#pragma unroll
          for (int jj = 0; jj < 4; ++jj) {
            float v = fast_tanh(acc[qd * 4 + jj] + ((const float*)&bq)[jj]);
            v = valid ? v : -2.0f;
            vmax[qd * 4 + jj] = fmaxf(vmax[qd * 4 + jj], v);
          }
        }
      }
    }
    __syncthreads();   // (2) X(it+1) ready; h1 free for overwrite
  }

  // reduce vmax across the 32 columns (each half-wave holds its own 16 rows)
#pragma unroll
  for (int r = 0; r < 16; ++r) {
    float v = vmax[r];
    v = fmaxf(v, __shfl_xor(v, 1, 64));
    v = fmaxf(v, __shfl_xor(v, 2, 64));
    v = fmaxf(v, __shfl_xor(v, 4, 64));
    v = fmaxf(v, __shfl_xor(v, 8, 64));
    v = fmaxf(v, __shfl_xor(v, 16, 64));
    vmax[r] = v;
  }
  float* hbuf = (float*)(lds + XS_OFF);   // reuse Xs region
  if (w < 4 && lrow == 0) {
#pragma unroll
    for (int r = 0; r < 16; ++r)
      hbuf[r0 + (r & 3) + 8 * (r >> 2) + 4 * hi5] = vmax[r];
  }
  __syncthreads();
  if (w >= 4 && lrow == 0) {
#pragma unroll
    for (int r = 0; r < 16; ++r) {
      int row = r0 + (r & 3) + 8 * (r >> 2) + 4 * hi5;
      hbuf[row] = fmaxf(hbuf[row], vmax[r]);
    }
  }
  __syncthreads();
  if (tid < 128) hpart[(size_t)bid * 128 + tid] = hbuf[tid];
}

// ---------------- k2: combine halves, project, tanh ----------------
__global__ void k2_proj(const float* __restrict__ hpart,
                        const float* __restrict__ qsw, const float* __restrict__ qsb,
                        const float* __restrict__ dsw, const float* __restrict__ dsb,
                        float* __restrict__ s_out) {
  int seq = blockIdx.x;        // 256
  int l = threadIdx.x;         // 64
  const float* sw = (seq < 64) ? qsw : dsw;
  const float* sb = (seq < 64) ? qsb : dsb;
  const float* h0 = hpart + (size_t)(2 * seq) * 128;
  const float* h1 = h0 + 128;
  float acc = sb[l];
  for (int k = 0; k < 128; ++k)
    acc += fmaxf(h0[k], h1[k]) * sw[l * 128 + k];
  s_out[(size_t)seq * 64 + l] = fast_tanh(acc);
}

// ---------------- k3: dots, gamma, softmax ----------------
__global__ void k3_softmax(const float* __restrict__ s_out,
                           const float* __restrict__ gw, const float* __restrict__ gb,
                           float* __restrict__ out) {
  int b = threadIdx.x;   // 64
  const float* qs = s_out + (size_t)b * 64;
  const float* ps = s_out + (size_t)(64 + b) * 64;
  const float* n0 = s_out + (size_t)(128 + b) * 64;
  const float* n1 = s_out + (size_t)(192 + b) * 64;
  float d0 = 0.f, d1 = 0.f, d2 = 0.f;
  for (int l = 0; l < 64; ++l) {
    float v = qs[l];
    d0 += v * ps[l];
    d1 += v * n0[l];
    d2 += v * n1[l];
  }
  float g = gw[0], bb = gb[0];
  d0 = g * d0 + bb; d1 = g * d1 + bb; d2 = g * d2 + bb;
  float m = fmaxf(d0, fmaxf(d1, d2));
  float e0 = expf(d0 - m), e1 = expf(d1 - m), e2 = expf(d2 - m);
  float inv = 1.0f / (e0 + e1 + e2);
  out[b * 3 + 0] = e0 * inv;
  out[b * 3 + 1] = e1 * inv;
  out[b * 3 + 2] = e2 * inv;
}

extern "C" void kernel_launch(void* const* d_in, const int* in_sizes, int n_in,
                              void* d_out, int out_size, void* d_ws, size_t ws_size,
                              hipStream_t stream) {
  const float* q    = (const float*)d_in[0];
  const float* pos  = (const float*)d_in[1];
  const float* negs = (const float*)d_in[2];
  const float* qw1  = (const float*)d_in[3];
  const float* qb1  = (const float*)d_in[4];
  const float* qw2  = (const float*)d_in[5];
  const float* qb2  = (const float*)d_in[6];
  const float* qsw  = (const float*)d_in[7];
  const float* qsb  = (const float*)d_in[8];
  const float* dw1  = (const float*)d_in[9];
  const float* db1  = (const float*)d_in[10];
  const float* dw2  = (const float*)d_in[11];
  const float* db2  = (const float*)d_in[12];
  const float* dsw  = (const float*)d_in[13];
  const float* dsb  = (const float*)d_in[14];
  const float* gw   = (const float*)d_in[15];
  const float* gb   = (const float*)d_in[16];
  float* out = (float*)d_out;

  char* ws = (char*)d_ws;
  unsigned short* W1p = (unsigned short*)(ws);             // 2*3*128*128 bf16 = 196608 B
  unsigned short* W2p = (unsigned short*)(ws + 196608);    // 196608 B
  float* hpart        = (float*)(ws + 393216);             // 512*128*4 = 262144 B
  float* s_out        = (float*)(ws + 655360);             // 256*64*4  = 65536 B

  hipFuncSetAttribute((const void*)cdssm_main,
                      hipFuncAttributeMaxDynamicSharedMemorySize, LDS_TOTAL);

  prep_kernel<<<768, 256, 0, stream>>>(qw1, qw2, dw1, dw2, W1p, W2p);
  cdssm_main<<<512, 512, LDS_TOTAL, stream>>>(q, pos, negs, W1p, W2p, qb1, qb2, db1, db2, hpart);
  k2_proj<<<256, 64, 0, stream>>>(hpart, qsw, qsb, dsw, dsb, s_out);
  k3_softmax<<<1, 64, 0, stream>>>(s_out, gw, gb, out);
}

// Round 3
// 556.319 us; speedup vs baseline: 1.0014x; 1.0014x over previous
//
#include <hip/hip_runtime.h>
#include <stdint.h>

// CDSSM: conv1(128ch,k3) -> tanh -> conv2(128ch,k3) -> tanh -> max_t -> proj -> tanh
//        then dots(q·pos, q·negs) -> gamma -> softmax.  B=64,T=2048,D=K=K2=128,L=64,J=2.
// R3: same T14 structure as R2, but fix the VGPR cap: __launch_bounds__(512,2) was
//     min-BLOCKS semantics -> 128-VGPR cap -> 97MB spill traffic. Now waves_per_eu(2,2)
//     -> 256-VGPR budget, no spills, async staging works as designed.

typedef __bf16 bf16x8 __attribute__((ext_vector_type(8)));
typedef __bf16 bf16x4 __attribute__((ext_vector_type(4)));
typedef float f32x16 __attribute__((ext_vector_type(16)));
typedef unsigned short u16x8 __attribute__((ext_vector_type(8)));

__device__ __forceinline__ unsigned short f2bf(float f) {
  unsigned u = __builtin_bit_cast(unsigned, f);
  u = u + 0x7FFFu + ((u >> 16) & 1u);   // RTNE
  return (unsigned short)(u >> 16);
}

__device__ __forceinline__ float fast_tanh(float x) {
  x = fminf(10.0f, fmaxf(-10.0f, x));
  float t = __builtin_amdgcn_exp2f(x * -2.8853900817779268f);   // e^{-2x}
  return (1.0f - t) * __builtin_amdgcn_rcpf(1.0f + t);
}

// ---------------- prep: fp32 [k][d][f] -> bf16 [br][f][k][d] ----------------
__global__ void prep_kernel(const float* __restrict__ qw1, const float* __restrict__ qw2,
                            const float* __restrict__ dw1, const float* __restrict__ dw2,
                            unsigned short* __restrict__ W1p, unsigned short* __restrict__ W2p) {
  int gid = blockIdx.x * 256 + threadIdx.x;          // 768*256 = 196608 exact
  int which = gid >= 98304;
  int e = gid - which * 98304;
  int br = e / 49152;
  int r  = e % 49152;
  int f  = r / 16384;
  int r2 = r % 16384;
  int k  = r2 / 128;
  int d  = r2 % 128;
  const float* src = which ? (br ? dw2 : qw2) : (br ? dw1 : qw1);
  float v = src[k * 384 + d * 3 + f];
  (which ? W2p : W1p)[e] = f2bf(v);
}

// ---------------- main fused conv kernel ----------------
// LDS layout (dynamic, 131584 B):
//  W1S_OFF : bf16 [2 taps][128 k][128 d], row-swizzled   (65536 B)
//  XS_OFF  : bf16 [128 slot][128 d], swizzled            (32768 B)
//  H1S_OFF : bf16 [126 slot][128 k], swizzled            (32256 B)
//  B1_OFF/B2_OFF : float[128] biases                     (1024 B)
#define W1S_OFF 0
#define XS_OFF  65536
#define H1S_OFF 98304
#define B1_OFF  130560
#define B2_OFF  131072
#define LDS_TOTAL 131584

__global__ __launch_bounds__(512)
__attribute__((amdgpu_waves_per_eu(2, 2)))
void cdssm_main(
    const float* __restrict__ q, const float* __restrict__ pos, const float* __restrict__ negs,
    const unsigned short* __restrict__ W1p, const unsigned short* __restrict__ W2p,
    const float* __restrict__ qb1, const float* __restrict__ qb2,
    const float* __restrict__ db1, const float* __restrict__ db2,
    float* __restrict__ hpart) {
  extern __shared__ char lds[];
  const int tid = threadIdx.x;
  const int bid = blockIdx.x;
  const int seq = bid >> 1;
  const int half = bid & 1;
  const int branch = (seq < 64) ? 0 : 1;
  const float* xptr = (seq < 64) ? (q + (size_t)seq * 2048 * 128)
                    : (seq < 128) ? (pos + (size_t)(seq - 64) * 2048 * 128)
                                  : (negs + (size_t)(seq - 128) * 2048 * 128);
  const float* b1g = branch ? db1 : qb1;
  const float* b2g = branch ? db2 : qb2;
  const int lo = half * 1022;
  const int hi = lo + 1022;   // 2*1022 = 2044 = T-4 outputs total

  // ---- stage W1 taps 0,1 into LDS (swizzled) + biases ----
  {
    const unsigned short* w1src = W1p + (size_t)branch * 49152;
    for (int ch = tid; ch < 4096; ch += 512) {       // 65536B / 16B
      int e = ch * 8;
      int f = e >> 14;
      int krow = (e >> 7) & 127;
      int d0 = e & 127;
      u16x8 v = *(const u16x8*)(w1src + ((f * 128 + krow) * 128 + d0));
      *(u16x8*)(lds + W1S_OFF + (f * 128 + krow) * 256 + ((d0 * 2) ^ ((krow & 15) << 4))) = v;
    }
    if (tid < 128) ((float*)(lds + B1_OFF))[tid] = b1g[tid];
    else if (tid < 256) ((float*)(lds + B2_OFF))[tid - 128] = b2g[tid - 128];
  }

  const int lane = tid & 63;
  const int w = tid >> 6;            // 8 waves
  const int lrow = lane & 31;
  const int hi5 = lane >> 5;         // k-group
  const int r0 = (w & 3) * 32;       // output-row tile
  const int cbase = (w >> 2) * 64;   // 2 col tiles of 32
  const int row1 = r0 + lrow;

  // register fragments: W1 tap2 (this wave's rows), all of W2 (this wave's rows)
  bf16x8 a1t2[8], a2s[24];
  {
    const unsigned short* w1src = W1p + (size_t)branch * 49152;
    const unsigned short* w2src = W2p + (size_t)branch * 49152;
#pragma unroll
    for (int kk = 0; kk < 8; ++kk)
      a1t2[kk] = __builtin_bit_cast(bf16x8,
          *(const u16x8*)(w1src + ((2 * 128 + row1) * 128 + kk * 16 + hi5 * 8)));
#pragma unroll
    for (int f = 0; f < 3; ++f)
#pragma unroll
      for (int kk = 0; kk < 8; ++kk)
        a2s[f * 8 + kk] = __builtin_bit_cast(bf16x8,
            *(const u16x8*)(w2src + ((f * 128 + row1) * 128 + kk * 16 + hi5 * 8)));
  }

  const int arow = row1 * 256;                 // + W1S_OFF + f*32768
  const int aswz = (lrow & 15) << 4;
  const int hi16 = hi5 * 16;                   // byte offset of k-group

  float vmax[16];
#pragma unroll
  for (int r = 0; r < 16; ++r) vmax[r] = -2.0f;

  // ---- prologue: stage X window 0 ----
  {
#pragma unroll
    for (int u = 0; u < 4; ++u) {
      int c2 = tid + 512 * u;            // chunk 0..2047
      int slot = c2 >> 4;
      int d0 = (c2 & 15) * 8;
      int t = lo + slot; if (t > 2047) t = 2047;
      const float* src = xptr + ((size_t)t * 128 + d0);
      float4 v0 = *(const float4*)src;
      float4 v1 = *(const float4*)(src + 4);
      bf16x8 o;
      o[0] = (__bf16)v0.x; o[1] = (__bf16)v0.y; o[2] = (__bf16)v0.z; o[3] = (__bf16)v0.w;
      o[4] = (__bf16)v1.x; o[5] = (__bf16)v1.y; o[6] = (__bf16)v1.z; o[7] = (__bf16)v1.w;
      *(bf16x8*)(lds + XS_OFF + slot * 256 + ((d0 * 2) ^ ((slot & 15) << 4))) = o;
    }
  }
  __syncthreads();   // X(0) + W1 + biases ready

  for (int it = 0; it < 9; ++it) {
    const int base = lo + it * 124;

    // ---- issue global loads for next window (latency hides under L1) ----
    float4 sreg[8];
    if (it < 8) {
      const int basen = base + 124;
#pragma unroll
      for (int u = 0; u < 4; ++u) {
        int c2 = tid + 512 * u;
        int slot = c2 >> 4;
        int d0 = (c2 & 15) * 8;
        int t = basen + slot; if (t > 2047) t = 2047;
        const float* src = xptr + ((size_t)t * 128 + d0);
        sreg[2 * u]     = *(const float4*)src;
        sreg[2 * u + 1] = *(const float4*)(src + 4);
      }
    }

    // ---- layer 1: h1[k, s] = tanh(b1 + sum_f sum_d W1[k,d,f] * X[base+s+f, d]) ----
    {
      int xb[2][3], xz[2][3];
#pragma unroll
      for (int cf = 0; cf < 2; ++cf)
#pragma unroll
        for (int f = 0; f < 3; ++f) {
          int s = cbase + cf * 32 + lrow + f; if (s > 127) s = 127;
          xb[cf][f] = XS_OFF + s * 256;
          xz[cf][f] = (s & 15) << 4;
        }
      f32x16 acc0, acc1;
#pragma unroll
      for (int r = 0; r < 16; ++r) { acc0[r] = 0.f; acc1[r] = 0.f; }
#pragma unroll
      for (int f = 0; f < 2; ++f)
#pragma unroll
        for (int kk = 0; kk < 8; ++kk) {
          bf16x8 af = __builtin_bit_cast(bf16x8,
              *(const u16x8*)(lds + W1S_OFF + f * 32768 + arow + ((kk * 32 + hi16) ^ aswz)));
          bf16x8 b0 = __builtin_bit_cast(bf16x8,
              *(const u16x8*)(lds + xb[0][f] + ((kk * 32 + hi16) ^ xz[0][f])));
          acc0 = __builtin_amdgcn_mfma_f32_32x32x16_bf16(af, b0, acc0, 0, 0, 0);
          bf16x8 b1v = __builtin_bit_cast(bf16x8,
              *(const u16x8*)(lds + xb[1][f] + ((kk * 32 + hi16) ^ xz[1][f])));
          acc1 = __builtin_amdgcn_mfma_f32_32x32x16_bf16(af, b1v, acc1, 0, 0, 0);
        }
#pragma unroll
      for (int kk = 0; kk < 8; ++kk) {
        bf16x8 b0 = __builtin_bit_cast(bf16x8,
            *(const u16x8*)(lds + xb[0][2] + ((kk * 32 + hi16) ^ xz[0][2])));
        acc0 = __builtin_amdgcn_mfma_f32_32x32x16_bf16(a1t2[kk], b0, acc0, 0, 0, 0);
        bf16x8 b1v = __builtin_bit_cast(bf16x8,
            *(const u16x8*)(lds + xb[1][2] + ((kk * 32 + hi16) ^ xz[1][2])));
        acc1 = __builtin_amdgcn_mfma_f32_32x32x16_bf16(a1t2[kk], b1v, acc1, 0, 0, 0);
      }
#pragma unroll
      for (int cf = 0; cf < 2; ++cf) {
        const f32x16 acc = cf ? acc1 : acc0;
        int s = cbase + cf * 32 + lrow;       // C layout: col = lane&31
        if (s < 126) {
          int wb = H1S_OFF + s * 256;
          int wz = (s & 15) << 4;
#pragma unroll
          for (int qd = 0; qd < 4; ++qd) {
            int k0 = r0 + qd * 8 + hi5 * 4;   // C rows: (reg&3)+8*(reg>>2)+4*hi
            float4 bq = *(const float4*)(lds + B1_OFF + k0 * 4);
            bf16x4 hv;
            hv[0] = (__bf16)fast_tanh(acc[qd * 4 + 0] + bq.x);
            hv[1] = (__bf16)fast_tanh(acc[qd * 4 + 1] + bq.y);
            hv[2] = (__bf16)fast_tanh(acc[qd * 4 + 2] + bq.z);
            hv[3] = (__bf16)fast_tanh(acc[qd * 4 + 3] + bq.w);
            *(bf16x4*)(lds + wb + ((k0 * 2) ^ wz)) = hv;
          }
        }
      }
    }
    __syncthreads();   // (1) h1 ready; all waves done reading X(it)

    // ---- layer 2: y2[k2, s2] = tanh(b2 + sum_f sum_c W2[k2,c,f] * h1[c, s2+f]) ----
    {
      int hb[2][3], hz[2][3];
#pragma unroll
      for (int cf = 0; cf < 2; ++cf)
#pragma unroll
        for (int f = 0; f < 3; ++f) {
          int s = cbase + cf * 32 + lrow + f; if (s > 125) s = 125;
          hb[cf][f] = H1S_OFF + s * 256;
          hz[cf][f] = (s & 15) << 4;
        }
      f32x16 acc0, acc1;
#pragma unroll
      for (int r = 0; r < 16; ++r) { acc0[r] = 0.f; acc1[r] = 0.f; }
#pragma unroll
      for (int f = 0; f < 3; ++f)
#pragma unroll
        for (int kk = 0; kk < 8; ++kk) {
          bf16x8 b0 = __builtin_bit_cast(bf16x8,
              *(const u16x8*)(lds + hb[0][f] + ((kk * 32 + hi16) ^ hz[0][f])));
          acc0 = __builtin_amdgcn_mfma_f32_32x32x16_bf16(a2s[f * 8 + kk], b0, acc0, 0, 0, 0);
          bf16x8 b1v = __builtin_bit_cast(bf16x8,
              *(const u16x8*)(lds + hb[1][f] + ((kk * 32 + hi16) ^ hz[1][f])));
          acc1 = __builtin_amdgcn_mfma_f32_32x32x16_bf16(a2s[f * 8 + kk], b1v, acc1, 0, 0, 0);
        }

      // ---- convert + write next X window (loads issued pre-L1; waits here) ----
      if (it < 8) {
#pragma unroll
        for (int u = 0; u < 4; ++u) {
          int c2 = tid + 512 * u;
          int slot = c2 >> 4;
          int d0 = (c2 & 15) * 8;
          const float* f0 = (const float*)&sreg[2 * u];
          bf16x8 o;
#pragma unroll
          for (int j = 0; j < 8; ++j) o[j] = (__bf16)f0[j];
          *(bf16x8*)(lds + XS_OFF + slot * 256 + ((d0 * 2) ^ ((slot & 15) << 4))) = o;
        }
      }

#pragma unroll
      for (int cf = 0; cf < 2; ++cf) {
        const f32x16 acc = cf ? acc1 : acc0;
        int s2 = cbase + cf * 32 + lrow;
        bool valid = (s2 < 124) && (base + s2 < hi);
#pragma unroll
        for (int qd = 0; qd < 4; ++qd) {
          int k0 = r0 + qd * 8 + hi5 * 4;
          float4 bq = *(const float4*)(lds + B2_OFF + k0 * 4);
#pragma unroll
          for (int jj = 0; jj < 4; ++jj) {
            float v = fast_tanh(acc[qd * 4 + jj] + ((const float*)&bq)[jj]);
            v = valid ? v : -2.0f;
            vmax[qd * 4 + jj] = fmaxf(vmax[qd * 4 + jj], v);
          }
        }
      }
    }
    __syncthreads();   // (2) X(it+1) ready; h1 free for overwrite
  }

  // reduce vmax across the 32 columns (each half-wave holds its own 16 rows)
#pragma unroll
  for (int r = 0; r < 16; ++r) {
    float v = vmax[r];
    v = fmaxf(v, __shfl_xor(v, 1, 64));
    v = fmaxf(v, __shfl_xor(v, 2, 64));
    v = fmaxf(v, __shfl_xor(v, 4, 64));
    v = fmaxf(v, __shfl_xor(v, 8, 64));
    v = fmaxf(v, __shfl_xor(v, 16, 64));
    vmax[r] = v;
  }
  float* hbuf = (float*)(lds + XS_OFF);   // reuse Xs region
  if (w < 4 && lrow == 0) {
#pragma unroll
    for (int r = 0; r < 16; ++r)
      hbuf[r0 + (r & 3) + 8 * (r >> 2) + 4 * hi5] = vmax[r];
  }
  __syncthreads();
  if (w >= 4 && lrow == 0) {
#pragma unroll
    for (int r = 0; r < 16; ++r) {
      int row = r0 + (r & 3) + 8 * (r >> 2) + 4 * hi5;
      hbuf[row] = fmaxf(hbuf[row], vmax[r]);
    }
  }
  __syncthreads();
  if (tid < 128) hpart[(size_t)bid * 128 + tid] = hbuf[tid];
}

// ---------------- k2: combine halves, project, tanh ----------------
__global__ void k2_proj(const float* __restrict__ hpart,
                        const float* __restrict__ qsw, const float* __restrict__ qsb,
                        const float* __restrict__ dsw, const float* __restrict__ dsb,
                        float* __restrict__ s_out) {
  int seq = blockIdx.x;        // 256
  int l = threadIdx.x;         // 64
  const float* sw = (seq < 64) ? qsw : dsw;
  const float* sb = (seq < 64) ? qsb : dsb;
  const float* h0 = hpart + (size_t)(2 * seq) * 128;
  const float* h1 = h0 + 128;
  float acc = sb[l];
  for (int k = 0; k < 128; ++k)
    acc += fmaxf(h0[k], h1[k]) * sw[l * 128 + k];
  s_out[(size_t)seq * 64 + l] = fast_tanh(acc);
}

// ---------------- k3: dots, gamma, softmax ----------------
__global__ void k3_softmax(const float* __restrict__ s_out,
                           const float* __restrict__ gw, const float* __restrict__ gb,
                           float* __restrict__ out) {
  int b = threadIdx.x;   // 64
  const float* qs = s_out + (size_t)b * 64;
  const float* ps = s_out + (size_t)(64 + b) * 64;
  const float* n0 = s_out + (size_t)(128 + b) * 64;
  const float* n1 = s_out + (size_t)(192 + b) * 64;
  float d0 = 0.f, d1 = 0.f, d2 = 0.f;
  for (int l = 0; l < 64; ++l) {
    float v = qs[l];
    d0 += v * ps[l];
    d1 += v * n0[l];
    d2 += v * n1[l];
  }
  float g = gw[0], bb = gb[0];
  d0 = g * d0 + bb; d1 = g * d1 + bb; d2 = g * d2 + bb;
  float m = fmaxf(d0, fmaxf(d1, d2));
  float e0 = expf(d0 - m), e1 = expf(d1 - m), e2 = expf(d2 - m);
  float inv = 1.0f / (e0 + e1 + e2);
  out[b * 3 + 0] = e0 * inv;
  out[b * 3 + 1] = e1 * inv;
  out[b * 3 + 2] = e2 * inv;
}

extern "C" void kernel_launch(void* const* d_in, const int* in_sizes, int n_in,
                              void* d_out, int out_size, void* d_ws, size_t ws_size,
                              hipStream_t stream) {
  const float* q    = (const float*)d_in[0];
  const float* pos  = (const float*)d_in[1];
  const float* negs = (const float*)d_in[2];
  const float* qw1  = (const float*)d_in[3];
  const float* qb1  = (const float*)d_in[4];
  const float* qw2  = (const float*)d_in[5];
  const float* qb2  = (const float*)d_in[6];
  const float* qsw  = (const float*)d_in[7];
  const float* qsb  = (const float*)d_in[8];
  const float* dw1  = (const float*)d_in[9];
  const float* db1  = (const float*)d_in[10];
  const float* dw2  = (const float*)d_in[11];
  const float* db2  = (const float*)d_in[12];
  const float* dsw  = (const float*)d_in[13];
  const float* dsb  = (const float*)d_in[14];
  const float* gw   = (const float*)d_in[15];
  const float* gb   = (const float*)d_in[16];
  float* out = (float*)d_out;

  char* ws = (char*)d_ws;
  unsigned short* W1p = (unsigned short*)(ws);             // 2*3*128*128 bf16 = 196608 B
  unsigned short* W2p = (unsigned short*)(ws + 196608);    // 196608 B
  float* hpart        = (float*)(ws + 393216);             // 512*128*4 = 262144 B
  float* s_out        = (float*)(ws + 655360);             // 256*64*4  = 65536 B

  hipFuncSetAttribute((const void*)cdssm_main,
                      hipFuncAttributeMaxDynamicSharedMemorySize, LDS_TOTAL);

  prep_kernel<<<768, 256, 0, stream>>>(qw1, qw2, dw1, dw2, W1p, W2p);
  cdssm_main<<<512, 512, LDS_TOTAL, stream>>>(q, pos, negs, W1p, W2p, qb1, qb2, db1, db2, hpart);
  k2_proj<<<256, 64, 0, stream>>>(hpart, qsw, qsb, dsw, dsb, s_out);
  k3_softmax<<<1, 64, 0, stream>>>(s_out, gw, gb, out);
}

// Round 4
// 182.835 us; speedup vs baseline: 3.0470x; 3.0427x over previous
//
#include <hip/hip_runtime.h>
#include <stdint.h>

// CDSSM: conv1(128ch,k3) -> tanh -> conv2(128ch,k3) -> tanh -> max_t -> proj -> tanh
//        then dots(q·pos, q·negs) -> gamma -> softmax.  B=64,T=2048,D=K=K2=128,L=64,J=2.
// R4: kill register-resident weights (a2s/a1t2 = 128 VGPRs pinned -> spills).
//     W1-tap2 + W2 prep-repacked fragment-major, loaded per-use (transient).
//     Freed regs fund T14 async staging into double-buffered X (window 124, stride 120).

typedef __bf16 bf16x8 __attribute__((ext_vector_type(8)));
typedef __bf16 bf16x4 __attribute__((ext_vector_type(4)));
typedef float f32x16 __attribute__((ext_vector_type(16)));
typedef unsigned short u16x8 __attribute__((ext_vector_type(8)));

__device__ __forceinline__ unsigned short f2bf(float f) {
  unsigned u = __builtin_bit_cast(unsigned, f);
  u = u + 0x7FFFu + ((u >> 16) & 1u);   // RTNE
  return (unsigned short)(u >> 16);
}

__device__ __forceinline__ float fast_tanh(float x) {
  x = fminf(10.0f, fmaxf(-10.0f, x));
  float t = __builtin_amdgcn_exp2f(x * -2.8853900817779268f);   // e^{-2x}
  return (1.0f - t) * __builtin_amdgcn_rcpf(1.0f + t);
}

// ---------------- prep ----------------
// W1p   [br][f][k][d]            : 98304 elems (taps 0,1 staged to LDS; tap2 unused here)
// W1t2f [br][kk][row][hi][j]     : 32768 elems (fragment-major A-operand, tap 2)
// W2f   [br][f][kk][row][hi][j]  : 98304 elems (fragment-major A-operand, all taps)
__global__ void prep_kernel(const float* __restrict__ qw1, const float* __restrict__ qw2,
                            const float* __restrict__ dw1, const float* __restrict__ dw2,
                            unsigned short* __restrict__ W1p, unsigned short* __restrict__ W1t2f,
                            unsigned short* __restrict__ W2f) {
  int gid = blockIdx.x * 256 + threadIdx.x;          // 896*256 = 229376 exact
  if (gid < 98304) {
    int e = gid;
    int br = e / 49152; int r = e % 49152;
    int f = r / 16384; int r2 = r % 16384;
    int k = r2 >> 7; int d = r2 & 127;
    const float* src = br ? dw1 : qw1;
    W1p[e] = f2bf(src[k * 384 + d * 3 + f]);
  } else if (gid < 131072) {
    int e = gid - 98304;
    int br = e >> 14; int r = e & 16383;
    int kk = r >> 11; int row = (r >> 4) & 127; int hi = (r >> 3) & 1; int j = r & 7;
    int c = kk * 16 + hi * 8 + j;
    const float* src = br ? dw1 : qw1;
    W1t2f[e] = f2bf(src[row * 384 + c * 3 + 2]);
  } else {
    int e = gid - 131072;
    int br = e / 49152; int r = e % 49152;
    int f = r / 16384; int r2 = r & 16383;
    int kk = r2 >> 11; int row = (r2 >> 4) & 127; int hi = (r2 >> 3) & 1; int j = r2 & 7;
    int c = kk * 16 + hi * 8 + j;
    const float* src = br ? dw2 : qw2;
    W2f[e] = f2bf(src[row * 384 + c * 3 + f]);
  }
}

// ---------------- main fused conv kernel ----------------
// LDS (dynamic, 161280 B):
//  W1S 0      : bf16 [2 taps][128 k][128 d], row-swizzled  (65536)
//  XA  65536  : bf16 [124 slot][128 d], swizzled           (31744)
//  XB  97280  : bf16 [124 slot][128 d], swizzled           (31744)
//  H1S 129024 : bf16 [122 slot][128 k], swizzled           (31232)
//  B1  160256 / B2 160768 : float[128] biases              (1024)
#define W1S_OFF 0
#define XA_OFF  65536
#define XB_OFF  97280
#define H1S_OFF 129024
#define B1_OFF  160256
#define B2_OFF  160768
#define LDS_TOTAL 161280
#define WIN 124        // X slots per window
#define STRIDE 120     // fresh outputs per iter
#define NIT 9          // ceil(1022/120)

__global__ __launch_bounds__(512) void cdssm_main(
    const float* __restrict__ q, const float* __restrict__ pos, const float* __restrict__ negs,
    const unsigned short* __restrict__ W1p, const unsigned short* __restrict__ W1t2f,
    const unsigned short* __restrict__ W2f,
    const float* __restrict__ qb1, const float* __restrict__ qb2,
    const float* __restrict__ db1, const float* __restrict__ db2,
    float* __restrict__ hpart) {
  extern __shared__ char lds[];
  const int tid = threadIdx.x;
  const int bid = blockIdx.x;
  const int seq = bid >> 1;
  const int half = bid & 1;
  const int branch = (seq < 64) ? 0 : 1;
  const float* xptr = (seq < 64) ? (q + (size_t)seq * 2048 * 128)
                    : (seq < 128) ? (pos + (size_t)(seq - 64) * 2048 * 128)
                                  : (negs + (size_t)(seq - 128) * 2048 * 128);
  const float* b1g = branch ? db1 : qb1;
  const float* b2g = branch ? db2 : qb2;
  const int lo = half * 1022;
  const int hi = lo + 1022;   // 2*1022 = 2044 = T-4 outputs total

  // ---- stage W1 taps 0,1 into LDS (swizzled) + biases ----
  {
    const unsigned short* w1src = W1p + (size_t)branch * 49152;
    for (int ch = tid; ch < 4096; ch += 512) {       // 65536B / 16B
      int e = ch * 8;
      int f = e >> 14;
      int krow = (e >> 7) & 127;
      int d0 = e & 127;
      u16x8 v = *(const u16x8*)(w1src + ((f * 128 + krow) * 128 + d0));
      *(u16x8*)(lds + W1S_OFF + (f * 128 + krow) * 256 + ((d0 * 2) ^ ((krow & 15) << 4))) = v;
    }
    if (tid < 128) ((float*)(lds + B1_OFF))[tid] = b1g[tid];
    else if (tid < 256) ((float*)(lds + B2_OFF))[tid - 128] = b2g[tid - 128];
  }

  const int lane = tid & 63;
  const int w = tid >> 6;            // 8 waves
  const int lrow = lane & 31;
  const int hi5 = lane >> 5;         // k-group
  const int r0 = (w & 3) * 32;       // output-row tile
  const int cbase = (w >> 2) * 64;   // 2 col tiles of 32
  const int row1 = r0 + lrow;

  const int arow = row1 * 256;                 // + W1S_OFF + f*32768
  const int aswz = (lrow & 15) << 4;
  const int hi16 = hi5 * 16;                   // byte offset of k-group

  // fragment-major weight bases (per-lane part folded in)
  const unsigned short* w1t2b = W1t2f + (size_t)branch * 16384 + row1 * 16 + hi5 * 8;
  const unsigned short* w2b   = W2f   + (size_t)branch * 49152 + row1 * 16 + hi5 * 8;

  float vmax[16];
#pragma unroll
  for (int r = 0; r < 16; ++r) vmax[r] = -2.0f;

  // ---- prologue: stage X window 0 into XA ----
  for (int c2 = tid; c2 < WIN * 16; c2 += 512) {
    int slot = c2 >> 4;
    int d0 = (c2 & 15) * 8;
    int t = lo + slot; if (t > 2047) t = 2047;
    const float* src = xptr + ((size_t)t * 128 + d0);
    float4 v0 = *(const float4*)src;
    float4 v1 = *(const float4*)(src + 4);
    bf16x8 o;
    o[0] = (__bf16)v0.x; o[1] = (__bf16)v0.y; o[2] = (__bf16)v0.z; o[3] = (__bf16)v0.w;
    o[4] = (__bf16)v1.x; o[5] = (__bf16)v1.y; o[6] = (__bf16)v1.z; o[7] = (__bf16)v1.w;
    *(bf16x8*)(lds + XA_OFF + slot * 256 + ((d0 * 2) ^ ((slot & 15) << 4))) = o;
  }
  __syncthreads();   // X(0) + W1 + biases ready

  for (int it = 0; it < NIT; ++it) {
    const int base = lo + it * STRIDE;
    const int xoff  = (it & 1) ? XB_OFF : XA_OFF;
    const int xoffn = (it & 1) ? XA_OFF : XB_OFF;

    // ---- layer 1: h1[k, s] = tanh(b1 + sum_f sum_d W1[k,d,f] * X[base+s+f, d]) ----
    {
      f32x16 acc0, acc1;
#pragma unroll
      for (int r = 0; r < 16; ++r) { acc0[r] = 0.f; acc1[r] = 0.f; }
#pragma unroll
      for (int f = 0; f < 2; ++f) {
        int s0v = cbase + lrow + f;       if (s0v > WIN - 1) s0v = WIN - 1;
        int s1v = cbase + 32 + lrow + f;  if (s1v > WIN - 1) s1v = WIN - 1;
        int b0b = xoff + s0v * 256, b0z = (s0v & 15) << 4;
        int b1b = xoff + s1v * 256, b1z = (s1v & 15) << 4;
#pragma unroll
        for (int kk = 0; kk < 8; ++kk) {
          bf16x8 af = __builtin_bit_cast(bf16x8,
              *(const u16x8*)(lds + W1S_OFF + f * 32768 + arow + ((kk * 32 + hi16) ^ aswz)));
          bf16x8 b0 = __builtin_bit_cast(bf16x8,
              *(const u16x8*)(lds + b0b + ((kk * 32 + hi16) ^ b0z)));
          acc0 = __builtin_amdgcn_mfma_f32_32x32x16_bf16(af, b0, acc0, 0, 0, 0);
          bf16x8 b1v = __builtin_bit_cast(bf16x8,
              *(const u16x8*)(lds + b1b + ((kk * 32 + hi16) ^ b1z)));
          acc1 = __builtin_amdgcn_mfma_f32_32x32x16_bf16(af, b1v, acc1, 0, 0, 0);
        }
      }
      {  // tap 2: A-fragments loaded per-use (transient)
        bf16x8 a1[8];
#pragma unroll
        for (int kk = 0; kk < 8; ++kk)
          a1[kk] = __builtin_bit_cast(bf16x8, *(const u16x8*)(w1t2b + kk * 2048));
        int s0v = cbase + lrow + 2;       if (s0v > WIN - 1) s0v = WIN - 1;
        int s1v = cbase + 32 + lrow + 2;  if (s1v > WIN - 1) s1v = WIN - 1;
        int b0b = xoff + s0v * 256, b0z = (s0v & 15) << 4;
        int b1b = xoff + s1v * 256, b1z = (s1v & 15) << 4;
#pragma unroll
        for (int kk = 0; kk < 8; ++kk) {
          bf16x8 b0 = __builtin_bit_cast(bf16x8,
              *(const u16x8*)(lds + b0b + ((kk * 32 + hi16) ^ b0z)));
          acc0 = __builtin_amdgcn_mfma_f32_32x32x16_bf16(a1[kk], b0, acc0, 0, 0, 0);
          bf16x8 b1v = __builtin_bit_cast(bf16x8,
              *(const u16x8*)(lds + b1b + ((kk * 32 + hi16) ^ b1z)));
          acc1 = __builtin_amdgcn_mfma_f32_32x32x16_bf16(a1[kk], b1v, acc1, 0, 0, 0);
        }
      }
      // epilogue: h1 slots 0..121
#pragma unroll
      for (int cf = 0; cf < 2; ++cf) {
        const f32x16 acc = cf ? acc1 : acc0;
        int s = cbase + cf * 32 + lrow;       // C layout: col = lane&31
        if (s < 122) {
          int wb = H1S_OFF + s * 256;
          int wz = (s & 15) << 4;
#pragma unroll
          for (int qd = 0; qd < 4; ++qd) {
            int k0 = r0 + qd * 8 + hi5 * 4;   // C rows: (reg&3)+8*(reg>>2)+4*hi
            float4 bq = *(const float4*)(lds + B1_OFF + k0 * 4);
            bf16x4 hv;
            hv[0] = (__bf16)fast_tanh(acc[qd * 4 + 0] + bq.x);
            hv[1] = (__bf16)fast_tanh(acc[qd * 4 + 1] + bq.y);
            hv[2] = (__bf16)fast_tanh(acc[qd * 4 + 2] + bq.z);
            hv[3] = (__bf16)fast_tanh(acc[qd * 4 + 3] + bq.w);
            *(bf16x4*)(lds + wb + ((k0 * 2) ^ wz)) = hv;
          }
        }
      }
    }
    __syncthreads();   // (1) h1 ready; all waves done reading X(cur)

    // ---- issue next-window global loads (latency hides under L2 MFMA) ----
    float4 va[8];
    const bool has4 = tid < (WIN * 16 - 1536);   // 1984 chunks
    if (it < NIT - 1) {
      const int basen = base + STRIDE;
#pragma unroll
      for (int u = 0; u < 3; ++u) {
        int c2 = tid + 512 * u;
        int slot = c2 >> 4;
        int d0 = (c2 & 15) * 8;
        int t = basen + slot; if (t > 2047) t = 2047;
        const float* src = xptr + ((size_t)t * 128 + d0);
        va[2 * u]     = *(const float4*)src;
        va[2 * u + 1] = *(const float4*)(src + 4);
      }
      if (has4) {
        int c2 = tid + 1536;
        int slot = c2 >> 4;
        int d0 = (c2 & 15) * 8;
        int t = basen + slot; if (t > 2047) t = 2047;
        const float* src = xptr + ((size_t)t * 128 + d0);
        va[6] = *(const float4*)src;
        va[7] = *(const float4*)(src + 4);
      }
    }

    // ---- layer 2: y2[k2, s2] = tanh(b2 + sum_f sum_c W2[k2,c,f] * h1[c, s2+f]) ----
    {
      f32x16 acc0, acc1;
#pragma unroll
      for (int r = 0; r < 16; ++r) { acc0[r] = 0.f; acc1[r] = 0.f; }
#pragma unroll 1
      for (int f = 0; f < 3; ++f) {
        bf16x8 a2[8];
#pragma unroll
        for (int kk = 0; kk < 8; ++kk)
          a2[kk] = __builtin_bit_cast(bf16x8, *(const u16x8*)(w2b + f * 16384 + kk * 2048));
        int s0v = cbase + lrow + f;       if (s0v > 121) s0v = 121;
        int s1v = cbase + 32 + lrow + f;  if (s1v > 121) s1v = 121;
        int hb0 = H1S_OFF + s0v * 256, hz0 = (s0v & 15) << 4;
        int hb1 = H1S_OFF + s1v * 256, hz1 = (s1v & 15) << 4;
#pragma unroll
        for (int kk = 0; kk < 8; ++kk) {
          bf16x8 b0 = __builtin_bit_cast(bf16x8,
              *(const u16x8*)(lds + hb0 + ((kk * 32 + hi16) ^ hz0)));
          acc0 = __builtin_amdgcn_mfma_f32_32x32x16_bf16(a2[kk], b0, acc0, 0, 0, 0);
          bf16x8 b1v = __builtin_bit_cast(bf16x8,
              *(const u16x8*)(lds + hb1 + ((kk * 32 + hi16) ^ hz1)));
          acc1 = __builtin_amdgcn_mfma_f32_32x32x16_bf16(a2[kk], b1v, acc1, 0, 0, 0);
        }
      }

      // ---- convert + write next X window into the other buffer ----
      if (it < NIT - 1) {
#pragma unroll
        for (int u = 0; u < 3; ++u) {
          int c2 = tid + 512 * u;
          int slot = c2 >> 4;
          int d0 = (c2 & 15) * 8;
          const float* f0 = (const float*)&va[2 * u];
          bf16x8 o;
#pragma unroll
          for (int j = 0; j < 8; ++j) o[j] = (__bf16)f0[j];
          *(bf16x8*)(lds + xoffn + slot * 256 + ((d0 * 2) ^ ((slot & 15) << 4))) = o;
        }
        if (has4) {
          int c2 = tid + 1536;
          int slot = c2 >> 4;
          int d0 = (c2 & 15) * 8;
          const float* f0 = (const float*)&va[6];
          bf16x8 o;
#pragma unroll
          for (int j = 0; j < 8; ++j) o[j] = (__bf16)f0[j];
          *(bf16x8*)(lds + xoffn + slot * 256 + ((d0 * 2) ^ ((slot & 15) << 4))) = o;
        }
      }

      // epilogue: running max over valid outputs
#pragma unroll
      for (int cf = 0; cf < 2; ++cf) {
        const f32x16 acc = cf ? acc1 : acc0;
        int s2 = cbase + cf * 32 + lrow;
        bool valid = (s2 < STRIDE) && (base + s2 < hi);
#pragma unroll
        for (int qd = 0; qd < 4; ++qd) {
          int k0 = r0 + qd * 8 + hi5 * 4;
          float4 bq = *(const float4*)(lds + B2_OFF + k0 * 4);
#pragma unroll
          for (int jj = 0; jj < 4; ++jj) {
            float v = fast_tanh(acc[qd * 4 + jj] + ((const float*)&bq)[jj]);
            v = valid ? v : -2.0f;
            vmax[qd * 4 + jj] = fmaxf(vmax[qd * 4 + jj], v);
          }
        }
      }
    }
    __syncthreads();   // (2) X(next) ready; h1 free for overwrite
  }

  // reduce vmax across the 32 columns (each half-wave holds its own 16 rows)
#pragma unroll
  for (int r = 0; r < 16; ++r) {
    float v = vmax[r];
    v = fmaxf(v, __shfl_xor(v, 1, 64));
    v = fmaxf(v, __shfl_xor(v, 2, 64));
    v = fmaxf(v, __shfl_xor(v, 4, 64));
    v = fmaxf(v, __shfl_xor(v, 8, 64));
    v = fmaxf(v, __shfl_xor(v, 16, 64));
    vmax[r] = v;
  }
  float* hbuf = (float*)(lds + XA_OFF);   // reuse X region
  if (w < 4 && lrow == 0) {
#pragma unroll
    for (int r = 0; r < 16; ++r)
      hbuf[r0 + (r & 3) + 8 * (r >> 2) + 4 * hi5] = vmax[r];
  }
  __syncthreads();
  if (w >= 4 && lrow == 0) {
#pragma unroll
    for (int r = 0; r < 16; ++r) {
      int row = r0 + (r & 3) + 8 * (r >> 2) + 4 * hi5;
      hbuf[row] = fmaxf(hbuf[row], vmax[r]);
    }
  }
  __syncthreads();
  if (tid < 128) hpart[(size_t)bid * 128 + tid] = hbuf[tid];
}

// ---------------- k2: combine halves, project, tanh ----------------
__global__ void k2_proj(const float* __restrict__ hpart,
                        const float* __restrict__ qsw, const float* __restrict__ qsb,
                        const float* __restrict__ dsw, const float* __restrict__ dsb,
                        float* __restrict__ s_out) {
  int seq = blockIdx.x;        // 256
  int l = threadIdx.x;         // 64
  const float* sw = (seq < 64) ? qsw : dsw;
  const float* sb = (seq < 64) ? qsb : dsb;
  const float* h0 = hpart + (size_t)(2 * seq) * 128;
  const float* h1 = h0 + 128;
  float acc = sb[l];
  for (int k = 0; k < 128; ++k)
    acc += fmaxf(h0[k], h1[k]) * sw[l * 128 + k];
  s_out[(size_t)seq * 64 + l] = fast_tanh(acc);
}

// ---------------- k3: dots, gamma, softmax ----------------
__global__ void k3_softmax(const float* __restrict__ s_out,
                           const float* __restrict__ gw, const float* __restrict__ gb,
                           float* __restrict__ out) {
  int b = threadIdx.x;   // 64
  const float* qs = s_out + (size_t)b * 64;
  const float* ps = s_out + (size_t)(64 + b) * 64;
  const float* n0 = s_out + (size_t)(128 + b) * 64;
  const float* n1 = s_out + (size_t)(192 + b) * 64;
  float d0 = 0.f, d1 = 0.f, d2 = 0.f;
  for (int l = 0; l < 64; ++l) {
    float v = qs[l];
    d0 += v * ps[l];
    d1 += v * n0[l];
    d2 += v * n1[l];
  }
  float g = gw[0], bb = gb[0];
  d0 = g * d0 + bb; d1 = g * d1 + bb; d2 = g * d2 + bb;
  float m = fmaxf(d0, fmaxf(d1, d2));
  float e0 = expf(d0 - m), e1 = expf(d1 - m), e2 = expf(d2 - m);
  float inv = 1.0f / (e0 + e1 + e2);
  out[b * 3 + 0] = e0 * inv;
  out[b * 3 + 1] = e1 * inv;
  out[b * 3 + 2] = e2 * inv;
}

extern "C" void kernel_launch(void* const* d_in, const int* in_sizes, int n_in,
                              void* d_out, int out_size, void* d_ws, size_t ws_size,
                              hipStream_t stream) {
  const float* q    = (const float*)d_in[0];
  const float* pos  = (const float*)d_in[1];
  const float* negs = (const float*)d_in[2];
  const float* qw1  = (const float*)d_in[3];
  const float* qb1  = (const float*)d_in[4];
  const float* qw2  = (const float*)d_in[5];
  const float* qb2  = (const float*)d_in[6];
  const float* qsw  = (const float*)d_in[7];
  const float* qsb  = (const float*)d_in[8];
  const float* dw1  = (const float*)d_in[9];
  const float* db1  = (const float*)d_in[10];
  const float* dw2  = (const float*)d_in[11];
  const float* db2  = (const float*)d_in[12];
  const float* dsw  = (const float*)d_in[13];
  const float* dsb  = (const float*)d_in[14];
  const float* gw   = (const float*)d_in[15];
  const float* gb   = (const float*)d_in[16];
  float* out = (float*)d_out;

  char* ws = (char*)d_ws;
  unsigned short* W1p   = (unsigned short*)(ws);             // 98304 elems = 196608 B
  unsigned short* W1t2f = (unsigned short*)(ws + 196608);    // 32768 elems = 65536 B
  unsigned short* W2f   = (unsigned short*)(ws + 262144);    // 98304 elems = 196608 B
  float* hpart          = (float*)(ws + 458752);             // 512*128*4 = 262144 B
  float* s_out          = (float*)(ws + 720896);             // 256*64*4  = 65536 B

  hipFuncSetAttribute((const void*)cdssm_main,
                      hipFuncAttributeMaxDynamicSharedMemorySize, LDS_TOTAL);

  prep_kernel<<<896, 256, 0, stream>>>(qw1, qw2, dw1, dw2, W1p, W1t2f, W2f);
  cdssm_main<<<512, 512, LDS_TOTAL, stream>>>(q, pos, negs, W1p, W1t2f, W2f,
                                              qb1, qb2, db1, db2, hpart);
  k2_proj<<<256, 64, 0, stream>>>(hpart, qsw, qsb, dsw, dsb, s_out);
  k3_softmax<<<1, 64, 0, stream>>>(s_out, gw, gb, out);
}